// Round 7
// baseline (435.147 us; speedup 1.0000x reference)
//
#include <hip/hip_runtime.h>

// Problem constants: B=512, D=1024, H1=512, H2=128
// Outputs (f32, concat): recover [512,1024], c2 [512,128], Jac [512,128,1024]
//
// R7 vs R6 (404.3):
//  - Diagnosis: jac blocks run in near-lockstep -> all compute, then all store; the CU
//    alternates [MFMA busy/HBM idle] and [HBM saturated/MFMA idle] => L4 ~ compute+write
//    serial (~100us) instead of max(compute,write) (~50us). R5(4blk/CU)==R6(2blk/CU)
//    confirms occupancy doesn't fix phase-synchronized alternation.
//  - Fix: per block, two sequential K-passes (batch bA then bA+1) over the same L2-hot
//    tiles; batch A's 64 stores are interleaved into pass B's 8 staging windows
//    (8 stores/tile, acked under the MFMA clusters). Only pass B's stores are exposed.
//  - Explicit #pragma unroll on both tile loops (compile-time acc indexing, rule #20).
//  - Front chain, recover path, swizzle, grid: R6-verbatim.

typedef _Float16 f16x8 __attribute__((ext_vector_type(8)));
typedef _Float16 f16x4 __attribute__((ext_vector_type(4)));
typedef float    f32x4 __attribute__((ext_vector_type(4)));
typedef float    f32x2 __attribute__((ext_vector_type(2)));

__device__ __forceinline__ void gld_lds16(const _Float16* src, _Float16* dst_wave_uniform) {
    __builtin_amdgcn_global_load_lds((const __attribute__((address_space(1))) unsigned int*)src,
                                     (__attribute__((address_space(3))) unsigned int*)dst_wave_uniform,
                                     16, 0, 0);
}

// ---------------- prep: W1 transpose->f16, W2 ->f16 ----------------
__device__ __forceinline__ void prep_dev(int bx, const float* __restrict__ W1,
                                         const float* __restrict__ W2,
                                         _Float16* __restrict__ W1T,
                                         _Float16* __restrict__ W2h) {
    if (bx < 512) {
        __shared__ float tile[32][33];
        int dt = (bx & 31) * 32, kt = (bx >> 5) * 32;
        int tx = threadIdx.x & 31, ty = threadIdx.x >> 5;  // 32 x 8
        #pragma unroll
        for (int r = 0; r < 32; r += 8)
            tile[ty + r][tx] = W1[(kt + ty + r) * 1024 + dt + tx];
        __syncthreads();
        #pragma unroll
        for (int r = 0; r < 32; r += 8)
            W1T[(size_t)(dt + ty + r) * 512 + kt + tx] = (_Float16)tile[tx][ty + r];
    } else {
        int i = (bx - 512) * 1024 + threadIdx.x * 4;  // 64 blocks cover 65536
        f32x4 v = *(const f32x4*)(W2 + i);
        f16x4 h;
        h.x = (_Float16)v.x; h.y = (_Float16)v.y; h.z = (_Float16)v.z; h.w = (_Float16)v.w;
        *(f16x4*)(W2h + i) = h;
    }
}

// ---------------- small fp32 GEMMs (accuracy-critical path) ----------------
// 32x64 tile, 256 threads, per-thread 2x4, BK=32, register-prefetch pipeline.
template <int EPI, bool TRANSB>
__device__ void gemm_dev(const float* __restrict__ A, const float* __restrict__ Bm,
                         const float* __restrict__ bias,
                         float* __restrict__ C, float* __restrict__ Cd,
                         _Float16* __restrict__ Ch,
                         int M, int N, int K, int m0, int n0) {
    __shared__ __align__(16) float As[32][34];
    __shared__ __align__(16) float Bs[32][68];
    const int tid = threadIdx.x, tx = tid & 15, ty = tid >> 4;
    const int ka  = tid & 31, ma  = tid >> 5;
    const int kbt = tid & 31, nbt = tid >> 5;
    const int nbf = tid & 63, kbf = tid >> 6;
    float acc[2][4] = {};
    float rA[4], rB[8];

    #pragma unroll
    for (int r = 0; r < 4; ++r) rA[r] = A[(size_t)(m0 + ma + 8 * r) * K + ka];
    if (TRANSB) {
        #pragma unroll
        for (int r = 0; r < 8; ++r) rB[r] = Bm[(size_t)(n0 + nbt + 8 * r) * K + kbt];
    } else {
        #pragma unroll
        for (int r = 0; r < 8; ++r) rB[r] = Bm[(size_t)(kbf + 4 * r) * N + n0 + nbf];
    }

    for (int k0 = 0; k0 < K; k0 += 32) {
        #pragma unroll
        for (int r = 0; r < 4; ++r) As[ka][ma + 8 * r] = rA[r];
        if (TRANSB) {
            #pragma unroll
            for (int r = 0; r < 8; ++r) Bs[kbt][nbt + 8 * r] = rB[r];
        } else {
            #pragma unroll
            for (int r = 0; r < 8; ++r) Bs[kbf + 4 * r][nbf] = rB[r];
        }
        const int k1 = k0 + 32;
        if (k1 < K) {
            #pragma unroll
            for (int r = 0; r < 4; ++r) rA[r] = A[(size_t)(m0 + ma + 8 * r) * K + k1 + ka];
            if (TRANSB) {
                #pragma unroll
                for (int r = 0; r < 8; ++r) rB[r] = Bm[(size_t)(n0 + nbt + 8 * r) * K + k1 + kbt];
            } else {
                #pragma unroll
                for (int r = 0; r < 8; ++r) rB[r] = Bm[(size_t)(k1 + kbf + 4 * r) * N + n0 + nbf];
            }
        }
        __syncthreads();
        #pragma unroll
        for (int k = 0; k < 32; ++k) {
            f32x2 av = *(const f32x2*)&As[k][ty * 2];
            f32x4 bv = *(const f32x4*)&Bs[k][tx * 4];
            #pragma unroll
            for (int i = 0; i < 2; ++i)
                #pragma unroll
                for (int j = 0; j < 4; ++j)
                    acc[i][j] += av[i] * bv[j];
        }
        __syncthreads();
    }

    #pragma unroll
    for (int i = 0; i < 2; ++i) {
        int row = m0 + ty * 2 + i;
        #pragma unroll
        for (int j = 0; j < 4; ++j) {
            int col = n0 + tx * 4 + j;
            float z = acc[i][j] + bias[col];
            float s = 1.f / (1.f + __expf(-z));
            if constexpr (EPI == 1) {
                C[(size_t)row * N + col]  = s;
                Cd[(size_t)row * N + col] = s * (1.f - s);
            } else {
                Ch[(size_t)row * N + col] = (_Float16)s;
            }
        }
    }
}

// ---------------- fused launch wrappers ----------------
__global__ __launch_bounds__(256) void fused_prep_gemm1(const float* __restrict__ x,
                                                        const float* __restrict__ W1,
                                                        const float* __restrict__ b1,
                                                        const float* __restrict__ W2,
                                                        _Float16* __restrict__ W1T,
                                                        _Float16* __restrict__ W2h,
                                                        float* __restrict__ c1,
                                                        float* __restrict__ s1p) {
    int bx = blockIdx.x;
    if (bx < 128) {
        gemm_dev<1, true>(x, W1, b1, c1, s1p, nullptr, 512, 512, 1024,
                          (bx >> 3) * 32, (bx & 7) * 64);
    } else {
        prep_dev(bx - 128, W1, W2, W1T, W2h);
    }
}

__global__ __launch_bounds__(256) void gemm2_kernel(const float* __restrict__ c1,
                                                    const float* __restrict__ W2,
                                                    const float* __restrict__ b2,
                                                    float* __restrict__ out_c2,
                                                    float* __restrict__ s2p) {
    gemm_dev<1, true>(c1, W2, b2, out_c2, s2p, nullptr, 512, 128, 512,
                      blockIdx.y * 32, blockIdx.x * 64);
}

__global__ __launch_bounds__(256) void gemm3_kernel(const float* __restrict__ out_c2,
                                                    const float* __restrict__ W2,
                                                    const float* __restrict__ b3,
                                                    _Float16* __restrict__ c3h) {
    gemm_dev<2, false>(out_c2, W2, b3, nullptr, nullptr, c3h, 512, 512, 128,
                       (blockIdx.x >> 3) * 32, (blockIdx.x & 7) * 64);
}

// ---------------- fused MFMA: recover (32 blocks) + Jac (2048 blocks, 2-pass) --------
// jac block = pair (bA, bA+1) x one 128-wide n-tile.
//   pass A: K-loop accumulating batch bA (tiles staged from L2-hot W2h/W1T).
//   pass B: re-stage same tiles, accumulate bA+1; batch A's stores interleave into
//           the 8 staging windows (write overlaps matrix-pipe work).
// recover: Out = c3h @ W1T^T + br (M=512), R5-verbatim.
__global__ __launch_bounds__(256, 2) void jacW_fused(const _Float16* __restrict__ c3h,
                                                     const _Float16* __restrict__ W2h,
                                                     const _Float16* __restrict__ W1T,
                                                     const float* __restrict__ s1p,
                                                     const float* __restrict__ s2p,
                                                     const float* __restrict__ br,
                                                     float* __restrict__ out_rec,
                                                     float* __restrict__ out_jac) {
    __shared__ __align__(16) _Float16 Wsl[128 * 64];  // A-src tile (W2h slice or c3h rows)
    __shared__ __align__(16) _Float16 Bsl[128 * 64];  // W1T tile
    __shared__ _Float16 S1h[2][512];                  // jac: s1p[bA], s1p[bA+1] as f16
    __shared__ float    S2s[2][128];                  // jac: s2p[bA], s2p[bA+1] / rec: bias

    const int tid = threadIdx.x;
    const int lane = tid & 63, wave = tid >> 6;
    const int wm = (wave >> 1) * 64, wn = (wave & 1) * 64;
    const int l15 = lane & 15, q = lane >> 4;
    const int bid = blockIdx.x;

    // staging geometry (proven swizzle): row = r*32 + wave*8 + (lane>>3),
    // source k-slot = (lane&7)^(lane>>3); LDS dest linear. Read slot = (kk/8+q)^(row&7).
    const int srow = wave * 8 + (lane >> 3);
    const int skof = ((lane & 7) ^ (lane >> 3)) * 8;

    if (bid < 32) {
        // ---------------- recover path (R5-verbatim) ----------------
        const int m0 = (bid >> 3) * 128, n0 = (bid & 7) * 128;
        const _Float16* Abase = c3h + (size_t)m0 * 512;
        const _Float16* Bbase = W1T + (size_t)n0 * 512;
        float* outp = out_rec + (size_t)m0 * 1024;
        if (tid < 128) S2s[0][tid] = br[n0 + tid];

        f32x4 acc[4][4];
        #pragma unroll
        for (int i = 0; i < 4; ++i)
            #pragma unroll
            for (int j = 0; j < 4; ++j) acc[i][j] = (f32x4){0.f, 0.f, 0.f, 0.f};

        for (int t = 0; t < 8; ++t) {
            const int kb = t * 64;
            #pragma unroll
            for (int r = 0; r < 4; ++r) {
                gld_lds16(Abase + (size_t)(r * 32 + srow) * 512 + kb + skof, Wsl + (r * 32 + wave * 8) * 64);
                gld_lds16(Bbase + (size_t)(r * 32 + srow) * 512 + kb + skof, Bsl + (r * 32 + wave * 8) * 64);
            }
            __syncthreads();
            #pragma unroll
            for (int kk = 0; kk < 64; kk += 32) {
                f16x8 af[4], bf[4];
                #pragma unroll
                for (int i = 0; i < 4; ++i)
                    af[i] = *(const f16x8*)(Wsl + (wm + i * 16 + l15) * 64 + ((kk + q * 8) ^ ((l15 & 7) * 8)));
                #pragma unroll
                for (int j = 0; j < 4; ++j)
                    bf[j] = *(const f16x8*)(Bsl + (wn + j * 16 + l15) * 64 + ((kk + q * 8) ^ ((l15 & 7) * 8)));
                #pragma unroll
                for (int i = 0; i < 4; ++i)
                    #pragma unroll
                    for (int j = 0; j < 4; ++j)
                        acc[i][j] = __builtin_amdgcn_mfma_f32_16x16x32_f16(af[i], bf[j], acc[i][j], 0, 0, 0);
            }
            __syncthreads();
        }

        #pragma unroll
        for (int i = 0; i < 4; ++i) {
            #pragma unroll
            for (int rg = 0; rg < 4; ++rg) {
                int ml = wm + i * 16 + q * 4 + rg;
                #pragma unroll
                for (int j = 0; j < 4; ++j) {
                    int cl = wn + j * 16 + l15;
                    __builtin_nontemporal_store(acc[i][j][rg] + S2s[0][cl],
                                                outp + (size_t)ml * 1024 + n0 + cl);
                }
            }
        }
        return;
    }

    // ---------------- jac path: pair (bA,bA+1), two K-passes ----------------
    const int jid = bid - 32;
    const int w = (jid & 7) * 256 + (jid >> 3);   // XCD-chunked bijection (2048 = 8*256)
    const int pair = w >> 3, n0 = (w & 7) * 128;
    const int bA = pair * 2;

    S1h[0][tid]       = (_Float16)s1p[(size_t)bA * 512 + tid];
    S1h[0][tid + 256] = (_Float16)s1p[(size_t)bA * 512 + 256 + tid];
    S1h[1][tid]       = (_Float16)s1p[(size_t)(bA + 1) * 512 + tid];
    S1h[1][tid + 256] = (_Float16)s1p[(size_t)(bA + 1) * 512 + 256 + tid];
    if (tid < 128) S2s[0][tid] = s2p[(size_t)bA * 128 + tid];
    else           S2s[1][tid - 128] = s2p[(size_t)(bA + 1) * 128 + (tid - 128)];

    const _Float16* Bbase = W1T + (size_t)n0 * 512;
    float* outA = out_jac + (size_t)bA * (128 * 1024);
    float* outB = outA + (128 * 1024);

    f32x4 accA[4][4], accB[4][4];
    #pragma unroll
    for (int i = 0; i < 4; ++i)
        #pragma unroll
        for (int j = 0; j < 4; ++j) {
            accA[i][j] = (f32x4){0.f, 0.f, 0.f, 0.f};
            accB[i][j] = (f32x4){0.f, 0.f, 0.f, 0.f};
        }

    // ---- pass A: batch bA ----
    #pragma unroll
    for (int t = 0; t < 8; ++t) {
        const int kb = t * 64;
        #pragma unroll
        for (int r = 0; r < 4; ++r) {
            gld_lds16(W2h   + (size_t)(r * 32 + srow) * 512 + kb + skof, Wsl + (r * 32 + wave * 8) * 64);
            gld_lds16(Bbase + (size_t)(r * 32 + srow) * 512 + kb + skof, Bsl + (r * 32 + wave * 8) * 64);
        }
        __syncthreads();
        #pragma unroll
        for (int kk = 0; kk < 64; kk += 32) {
            const f16x8 sfA = *(const f16x8*)(&S1h[0][kb + kk + q * 8]);
            f16x8 bf[4];
            #pragma unroll
            for (int j = 0; j < 4; ++j)
                bf[j] = *(const f16x8*)(Bsl + (wn + j * 16 + l15) * 64 + ((kk + q * 8) ^ ((l15 & 7) * 8)));
            #pragma unroll
            for (int i = 0; i < 4; ++i) {
                const f16x8 wf = *(const f16x8*)(Wsl + (wm + i * 16 + l15) * 64 + ((kk + q * 8) ^ ((l15 & 7) * 8)));
                const f16x8 af = wf * sfA;
                #pragma unroll
                for (int j = 0; j < 4; ++j)
                    accA[i][j] = __builtin_amdgcn_mfma_f32_16x16x32_f16(af, bf[j], accA[i][j], 0, 0, 0);
            }
        }
        __syncthreads();
    }

    // ---- pass B: batch bA+1; A's stores interleave into the staging windows ----
    #pragma unroll
    for (int t = 0; t < 8; ++t) {
        const int kb = t * 64;
        #pragma unroll
        for (int r = 0; r < 4; ++r) {
            gld_lds16(W2h   + (size_t)(r * 32 + srow) * 512 + kb + skof, Wsl + (r * 32 + wave * 8) * 64);
            gld_lds16(Bbase + (size_t)(r * 32 + srow) * 512 + kb + skof, Bsl + (r * 32 + wave * 8) * 64);
        }
        {   // 8 stores of accA (chunk t): i = t>>1, rg = (t&1)*2 + {0,1}, j = 0..3
            const int i = t >> 1;
            #pragma unroll
            for (int r2 = 0; r2 < 2; ++r2) {
                const int rg = (t & 1) * 2 + r2;
                const int ml = wm + i * 16 + q * 4 + rg;
                const float rs = S2s[0][ml];
                #pragma unroll
                for (int j = 0; j < 4; ++j) {
                    const int cl = wn + j * 16 + l15;
                    __builtin_nontemporal_store(accA[i][j][rg] * rs,
                                                outA + (size_t)ml * 1024 + n0 + cl);
                }
            }
        }
        __syncthreads();
        #pragma unroll
        for (int kk = 0; kk < 64; kk += 32) {
            const f16x8 sfB = *(const f16x8*)(&S1h[1][kb + kk + q * 8]);
            f16x8 bf[4];
            #pragma unroll
            for (int j = 0; j < 4; ++j)
                bf[j] = *(const f16x8*)(Bsl + (wn + j * 16 + l15) * 64 + ((kk + q * 8) ^ ((l15 & 7) * 8)));
            #pragma unroll
            for (int i = 0; i < 4; ++i) {
                const f16x8 wf = *(const f16x8*)(Wsl + (wm + i * 16 + l15) * 64 + ((kk + q * 8) ^ ((l15 & 7) * 8)));
                const f16x8 af = wf * sfB;
                #pragma unroll
                for (int j = 0; j < 4; ++j)
                    accB[i][j] = __builtin_amdgcn_mfma_f32_16x16x32_f16(af, bf[j], accB[i][j], 0, 0, 0);
            }
        }
        __syncthreads();
    }

    // ---- tail: batch B stores (exposed) ----
    #pragma unroll
    for (int i = 0; i < 4; ++i) {
        #pragma unroll
        for (int rg = 0; rg < 4; ++rg) {
            const int ml = wm + i * 16 + q * 4 + rg;
            const float rs = S2s[1][ml];
            #pragma unroll
            for (int j = 0; j < 4; ++j) {
                const int cl = wn + j * 16 + l15;
                __builtin_nontemporal_store(accB[i][j][rg] * rs,
                                            outB + (size_t)ml * 1024 + n0 + cl);
            }
        }
    }
}

extern "C" void kernel_launch(void* const* d_in, const int* in_sizes, int n_in,
                              void* d_out, int out_size, void* d_ws, size_t ws_size,
                              hipStream_t stream) {
    const float* x  = (const float*)d_in[0];
    const float* W1 = (const float*)d_in[1];
    const float* b1 = (const float*)d_in[2];
    const float* W2 = (const float*)d_in[3];
    const float* b2 = (const float*)d_in[4];
    const float* b3 = (const float*)d_in[5];
    const float* br = (const float*)d_in[6];

    float* out_rec = (float*)d_out;               // 512*1024
    float* out_c2  = out_rec + 512 * 1024;        // 512*128
    float* out_jac = out_c2 + 512 * 128;          // 512*128*1024

    char* ws = (char*)d_ws;
    _Float16* W1T = (_Float16*)(ws);               // 1 MB   [1024][512]
    _Float16* W2h = (_Float16*)(ws + 0x100000);    // 128 KB [128][512]
    float*    c1  = (float*)(ws + 0x120000);       // 1 MB
    float*    s1p = (float*)(ws + 0x220000);       // 1 MB
    float*    s2p = (float*)(ws + 0x320000);       // 256 KB
    _Float16* c3h = (_Float16*)(ws + 0x360000);    // 512 KB (ends 0x3E0000, ~3.9 MB total)

    // L1: c1 GEMM (128 blocks) + prep (576 blocks)
    fused_prep_gemm1<<<704, 256, 0, stream>>>(x, W1, b1, W2, W1T, W2h, c1, s1p);
    // L2: c2 (+ s2p)
    gemm2_kernel<<<dim3(2, 16), 256, 0, stream>>>(c1, W2, b2, out_c2, s2p);
    // L3: c3h
    gemm3_kernel<<<128, 256, 0, stream>>>(out_c2, W2, b3, c3h);
    // L4: recover (32 blocks) + Jac (2048 blocks, two-pass with interleaved stores)
    jacW_fused<<<2080, 256, 0, stream>>>(c3h, W2h, W1T, s1p, s2p, br, out_rec, out_jac);
}